// Round 2
// baseline (451.029 us; speedup 1.0000x reference)
//
#include <hip/hip_runtime.h>
#include <stdint.h>

using short8  = __attribute__((ext_vector_type(8))) short;   // 8 x bf16 (4 VGPRs)
using floatx4 = __attribute__((ext_vector_type(4))) float;   // MFMA acc
using u16 = unsigned short;
using u32 = unsigned int;

#define MFMA16(A,B,C) __builtin_amdgcn_mfma_f32_16x16x32_bf16((A),(B),(C),0,0,0)

static __device__ __forceinline__ u16 f2bf(float f) {
  u32 u = __float_as_uint(f);
  u += 0x7fffu + ((u >> 16) & 1u);   // RNE
  return (u16)(u >> 16);
}
static __device__ __forceinline__ u32 pack2(float a, float b) {
  return (u32)f2bf(a) | ((u32)f2bf(b) << 16);
}

// CK-style global->LDS direct copy, 16B per lane. LDS dest must be wave-uniform
// base (HW adds lane*16); global src is per-lane (carries the swizzle).
static __device__ __forceinline__ void gl2lds16(const void* g, void* l) {
  auto gp = reinterpret_cast<__attribute__((address_space(1))) u32*>(
      reinterpret_cast<uintptr_t>(g));
  auto lp = reinterpret_cast<__attribute__((address_space(3))) u32*>(
      reinterpret_cast<uintptr_t>(l));
  __builtin_amdgcn_global_load_lds(gp, lp, 16, 0, 0);
}

// ---------------- prep: fp32 -> bf16 convert ----------------
__global__ __launch_bounds__(256) void cvt_x(const float* __restrict__ x,
                                             u16* __restrict__ xb) {
  size_t i = ((size_t)blockIdx.x * 256 + threadIdx.x) * 8;
  float4 a = *(const float4*)&x[i];
  float4 b = *(const float4*)&x[i + 4];
  uint4 pk = make_uint4(pack2(a.x, a.y), pack2(a.z, a.w),
                        pack2(b.x, b.y), pack2(b.z, b.w));
  *(uint4*)&xb[i] = pk;
}

// W[K][N] fp32 -> Wt[N][K] bf16 (tiled 64x64 transpose through LDS)
__global__ __launch_bounds__(256) void tr_cvt(const float* __restrict__ W,
                                              u16* __restrict__ Wt,
                                              int K, int N) {
  __shared__ u16 t[64][72];   // +8 pad
  const int tid = threadIdx.x;
  const int n0 = blockIdx.x * 64, k0 = blockIdx.y * 64;
#pragma unroll
  for (int i = 0; i < 4; ++i) {
    int c = i * 256 + tid;
    int r = c >> 4, co = (c & 15) * 4;
    float4 v = *(const float4*)&W[(size_t)(k0 + r) * N + n0 + co];
    uint2 pk; pk.x = pack2(v.x, v.y); pk.y = pack2(v.z, v.w);
    *(uint2*)&t[r][co] = pk;
  }
  __syncthreads();
#pragma unroll
  for (int i = 0; i < 2; ++i) {
    int c = i * 256 + tid;
    int n = c >> 3, ko = (c & 7) * 8;
    u16 o[8];
#pragma unroll
    for (int j = 0; j < 8; ++j) o[j] = t[ko + j][n];
    uint4 pk = make_uint4((u32)o[0] | ((u32)o[1] << 16), (u32)o[2] | ((u32)o[3] << 16),
                          (u32)o[4] | ((u32)o[5] << 16), (u32)o[6] | ((u32)o[7] << 16));
    *(uint4*)&Wt[(size_t)(n0 + n) * K + k0 + ko] = pk;
  }
}

// ---------------- GEMM: A[M][K] bf16 x Bt[N][K] bf16 ----------------
// 128x128 tile, BK=64, 4 waves (2x2), each 64x64. Double-buffered LDS via
// global_load_lds(16B) with pre-swizzled global source (XOR chunk swizzle).
// MODE 0: epilogue routes QKV (Q scaled by SCALE*log2e, V transposed).
// MODE 1: fp32 + bias -> d_out.
template <int MODE>
__global__ __launch_bounds__(256)
void gemm_bt(const u16* __restrict__ A, const u16* __restrict__ Bt, int Kd,
             const float* __restrict__ bias, float* __restrict__ outF,
             u16* __restrict__ Qo, u16* __restrict__ Ko, u16* __restrict__ Vto) {
  __shared__ __align__(16) u16 lA[2][128 * 64];
  __shared__ __align__(16) u16 lB[2][128 * 64];
  const int tid = threadIdx.x;
  const int l = tid & 63, w = tid >> 6;
  const int g = l >> 4, ll = l & 15, l7 = l & 7, rl = l >> 3;
  const int mt = blockIdx.x, nt = blockIdx.y;
  const int wr = w >> 1, wc = w & 1;
  const int swz = ((l7 ^ rl) << 4);  // inverse-swizzle on the global source

  const char* srcA = (const char*)(A + (size_t)(mt * 128 + w * 32 + rl) * Kd) + swz;
  const char* srcB = (const char*)(Bt + (size_t)(nt * 128 + w * 32 + rl) * Kd) + swz;
  const size_t rstep = (size_t)8 * Kd * 2;

  floatx4 acc[4][4];
#pragma unroll
  for (int i = 0; i < 4; ++i)
#pragma unroll
    for (int j = 0; j < 4; ++j) acc[i][j] = floatx4{0.f, 0.f, 0.f, 0.f};

  const int NT = Kd >> 6;
  auto stage = [&](int t, int buf) {
    const char* a = srcA + (size_t)t * 128;
    const char* b = srcB + (size_t)t * 128;
    char* la = (char*)&lA[buf][0] + w * 4096;
    char* lb = (char*)&lB[buf][0] + w * 4096;
#pragma unroll
    for (int j = 0; j < 4; ++j) {
      gl2lds16(a + j * rstep, la + j * 1024);
      gl2lds16(b + j * rstep, lb + j * 1024);
    }
  };

  stage(0, 0);
  int cur = 0;
  for (int t = 0; t < NT; ++t) {
    __syncthreads();                       // drains vmcnt then barrier
    if (t + 1 < NT) stage(t + 1, cur ^ 1); // prefetch overlaps compute
    const u16* la = &lA[cur][0];
    const u16* lb = &lB[cur][0];
#pragma unroll
    for (int ks = 0; ks < 2; ++ks) {
      short8 af[4], bfr[4];
#pragma unroll
      for (int mi = 0; mi < 4; ++mi) {
        int row = wr * 64 + mi * 16 + ll;
        af[mi] = *(const short8*)&la[row * 64 + ((ks * 32 + g * 8) ^ (l7 * 8))];
      }
#pragma unroll
      for (int ni = 0; ni < 4; ++ni) {
        int row = wc * 64 + ni * 16 + ll;
        bfr[ni] = *(const short8*)&lb[row * 64 + ((ks * 32 + g * 8) ^ (l7 * 8))];
      }
#pragma unroll
      for (int mi = 0; mi < 4; ++mi)
#pragma unroll
        for (int ni = 0; ni < 4; ++ni)
          acc[mi][ni] = MFMA16(af[mi], bfr[ni], acc[mi][ni]);
    }
    cur ^= 1;
  }

  if (MODE == 0) {
    const float QS = 0.18033688011112042f;  // 1/8 * log2(e)
#pragma unroll
    for (int ni = 0; ni < 4; ++ni) {
      int np = nt * 128 + wc * 64 + ni * 16 + ll;
      int tsel = np >> 10, hh = (np >> 6) & 15, dd = np & 63;
      float bv = bias[np];
#pragma unroll
      for (int mi = 0; mi < 4; ++mi) {
        int n0r = mt * 128 + wr * 64 + mi * 16 + g * 4;
        floatx4 v = acc[mi][ni];
        if (tsel == 0) {
#pragma unroll
          for (int i = 0; i < 4; ++i)
            Qo[((size_t)hh * 4096 + n0r + i) * 64 + dd] = f2bf((v[i] + bv) * QS);
        } else if (tsel == 1) {
#pragma unroll
          for (int i = 0; i < 4; ++i)
            Ko[((size_t)hh * 4096 + n0r + i) * 64 + dd] = f2bf(v[i] + bv);
        } else {  // V transposed: Vt[h][d][n]
          uint2 pk; pk.x = pack2(v[0] + bv, v[1] + bv); pk.y = pack2(v[2] + bv, v[3] + bv);
          *(uint2*)&Vto[((size_t)hh * 64 + dd) * 4096 + n0r] = pk;
        }
      }
    }
  } else {
#pragma unroll
    for (int ni = 0; ni < 4; ++ni) {
      int col = nt * 128 + wc * 64 + ni * 16 + ll;
      float bv = bias[col];
#pragma unroll
      for (int mi = 0; mi < 4; ++mi) {
        int r0 = mt * 128 + wr * 64 + mi * 16 + g * 4;
#pragma unroll
        for (int i = 0; i < 4; ++i)
          outF[(size_t)(r0 + i) * 1024 + col] = acc[mi][ni][i] + bv;
      }
    }
  }
}

// ---------------- flash attention ----------------
// grid (32 qblocks, 16 heads), 256 thr = 4 waves, wave owns 32 q-rows.
// Swapped QK^T: S^T = mfma(K, Q) so each lane holds key-slices of its q col
// (softmax reduce = in-reg + shfl_xor 16/32). P goes through swizzled LDS;
// PV computes O^T = mfma(V^T, P^T). K/V read direct from global (L2-resident:
// per-head K+V = 1 MB).
__global__ __launch_bounds__(256)
void attn_kernel(const u16* __restrict__ Qb, const u16* __restrict__ Kb,
                 const u16* __restrict__ Vt, u16* __restrict__ aout) {
  __shared__ __align__(16) char plds[4 * 8192];
  const int tid = threadIdx.x, l = tid & 63, w = tid >> 6;
  const int g = l >> 4, ll = l & 15, l7 = l & 7;
  const int h = blockIdx.y, qb = blockIdx.x;
  const int q0 = qb * 128 + w * 32;
  const u16* Qh = Qb + (size_t)h * 4096 * 64;
  const u16* Kh = Kb + (size_t)h * 4096 * 64;
  const u16* Vh = Vt + (size_t)h * 64 * 4096;
  char* myp = plds + w * 8192;

  short8 qf[2][2];
#pragma unroll
  for (int c = 0; c < 2; ++c)
#pragma unroll
    for (int ks = 0; ks < 2; ++ks)
      qf[c][ks] = *(const short8*)&Qh[(size_t)(q0 + c * 16 + ll) * 64 + ks * 32 + g * 8];

  float m[2] = {-1e30f, -1e30f}, lsum[2] = {0.f, 0.f};
  floatx4 o[4][2];
#pragma unroll
  for (int fd = 0; fd < 4; ++fd)
#pragma unroll
    for (int c = 0; c < 2; ++c) o[fd][c] = floatx4{0.f, 0.f, 0.f, 0.f};

  for (int kt = 0; kt < 32; ++kt) {
    const u16* Kt = Kh + (size_t)kt * 128 * 64;
    floatx4 s[2][8];
#pragma unroll
    for (int c = 0; c < 2; ++c)
#pragma unroll
      for (int fr = 0; fr < 8; ++fr) s[c][fr] = floatx4{0.f, 0.f, 0.f, 0.f};

#pragma unroll
    for (int ks = 0; ks < 2; ++ks) {
      short8 kf[8];
#pragma unroll
      for (int fr = 0; fr < 8; ++fr)
        kf[fr] = *(const short8*)&Kt[(size_t)(fr * 16 + ll) * 64 + ks * 32 + g * 8];
#pragma unroll
      for (int fr = 0; fr < 8; ++fr)
#pragma unroll
        for (int c = 0; c < 2; ++c)
          s[c][fr] = MFMA16(kf[fr], qf[c][ks], s[c][fr]);
    }

    // online softmax (base-2; scale folded into Q)
#pragma unroll
    for (int c = 0; c < 2; ++c) {
      float tm = -1e30f;
#pragma unroll
      for (int fr = 0; fr < 8; ++fr)
#pragma unroll
        for (int i = 0; i < 4; ++i) tm = fmaxf(tm, s[c][fr][i]);
      tm = fmaxf(tm, __shfl_xor(tm, 16));
      tm = fmaxf(tm, __shfl_xor(tm, 32));
      float mn = fmaxf(m[c], tm);
      float al = __builtin_amdgcn_exp2f(m[c] - mn);
      float rs = 0.f;
#pragma unroll
      for (int fr = 0; fr < 8; ++fr)
#pragma unroll
        for (int i = 0; i < 4; ++i) {
          float p = __builtin_amdgcn_exp2f(s[c][fr][i] - mn);
          s[c][fr][i] = p;
          rs += p;
        }
      rs += __shfl_xor(rs, 16);
      rs += __shfl_xor(rs, 32);
      lsum[c] = lsum[c] * al + rs;
      m[c] = mn;
#pragma unroll
      for (int fd = 0; fd < 4; ++fd) o[fd][c] *= al;
    }

    // P -> LDS as [32 q][128 key] bf16, XOR-swizzled (write/read same involution)
#pragma unroll
    for (int c = 0; c < 2; ++c) {
      char* rowp = myp + (c * 16 + ll) * 256;
#pragma unroll
      for (int fr = 0; fr < 8; ++fr) {
        uint2 pk;
        pk.x = pack2(s[c][fr][0], s[c][fr][1]);
        pk.y = pack2(s[c][fr][2], s[c][fr][3]);
        *(uint2*)(rowp + ((fr * 32 + g * 8) ^ (l7 * 16))) = pk;
      }
    }

    // PV: O^T += V^T x P^T
#pragma unroll
    for (int ks2 = 0; ks2 < 4; ++ks2) {
      short8 vf[4];
#pragma unroll
      for (int fd = 0; fd < 4; ++fd)
        vf[fd] = *(const short8*)&Vh[(size_t)(fd * 16 + ll) * 4096 + kt * 128 + ks2 * 32 + g * 8];
      short8 pf[2];
#pragma unroll
      for (int c = 0; c < 2; ++c)
        pf[c] = *(const short8*)(myp + (c * 16 + ll) * 256 + ((ks2 * 64 + g * 16) ^ (l7 * 16)));
#pragma unroll
      for (int fd = 0; fd < 4; ++fd)
#pragma unroll
        for (int c = 0; c < 2; ++c)
          o[fd][c] = MFMA16(vf[fd], pf[c], o[fd][c]);
    }
  }

  // normalize + write attn_out[n][h*64+d] bf16
#pragma unroll
  for (int c = 0; c < 2; ++c) {
    float inv = 1.f / lsum[c];
    int n = q0 + c * 16 + ll;
#pragma unroll
    for (int fd = 0; fd < 4; ++fd) {
      uint2 pk;
      pk.x = pack2(o[fd][c][0] * inv, o[fd][c][1] * inv);
      pk.y = pack2(o[fd][c][2] * inv, o[fd][c][3] * inv);
      *(uint2*)&aout[(size_t)n * 1024 + h * 64 + fd * 16 + g * 4] = pk;
    }
  }
}

extern "C" void kernel_launch(void* const* d_in, const int* in_sizes, int n_in,
                              void* d_out, int out_size, void* d_ws, size_t ws_size,
                              hipStream_t stream) {
  const float* x    = (const float*)d_in[0];
  const float* Wqkv = (const float*)d_in[1];
  const float* bqkv = (const float*)d_in[2];
  const float* Wout = (const float*)d_in[3];
  const float* bout = (const float*)d_in[4];
  float* out = (float*)d_out;

  // d_ws usage: 24 MB total (defensive — ws_size is harness-chosen).
  u16* ws    = (u16*)d_ws;
  u16* xb    = ws;                            // 4M u16 = 8 MB (reused as aout)
  u16* wqkvT = xb + (size_t)4096 * 1024;      // 6 MB
  u16* woutT = wqkvT + (size_t)3072 * 1024;   // 2 MB
  u16* Vt    = woutT + (size_t)1024 * 1024;   // 8 MB
  u16* aout  = xb;                            // alias: xb dead after gemm<0>

  // Q and K live in d_out (16 MB fp32 buffer; holds exactly 2 x 8 MB bf16).
  // Both are dead before gemm<1> rewrites d_out in full.
  u16* Qb = (u16*)d_out;                      // 8 MB
  u16* Kb = Qb + (size_t)16 * 4096 * 64;      // 8 MB

  cvt_x<<<2048, 256, 0, stream>>>(x, xb);
  tr_cvt<<<dim3(48, 16), 256, 0, stream>>>(Wqkv, wqkvT, 1024, 3072);
  tr_cvt<<<dim3(16, 16), 256, 0, stream>>>(Wout, woutT, 1024, 1024);
  gemm_bt<0><<<dim3(32, 24), 256, 0, stream>>>(xb, wqkvT, 1024, bqkv, nullptr, Qb, Kb, Vt);
  attn_kernel<<<dim3(32, 16), 256, 0, stream>>>(Qb, Kb, Vt, aout);
  gemm_bt<1><<<dim3(32, 8), 256, 0, stream>>>(aout, woutT, 1024, bout, out,
                                              nullptr, nullptr, nullptr);
}